// Round 4
// baseline (228.962 us; speedup 1.0000x reference)
//
#include <hip/hip_runtime.h>

// BNN conv3d forward: x (8,32,16,160,160) f32, w (32,32,1,3,3) f32
// out[n,o,d,h,w] = sum_i sum_{kh,kw} x[n,i,d,h+kh-1,w+kw-1] * we[o,i,kh,kw]
// we[o,i,kh,kw] = (mean_t |w[o,i,t]|) * sign(w[o,i,kh,kw])
//
// Implicit GEMM on mfma_f32_16x16x32_f16. Two kernels:
//  (1) prep: weight fragments (18 KB) -> d_ws  (runs every launch, tiny)
//  (2) conv: per block 4 rows x 160 w; ALL staging loads issued at entry
//      (T14 issue-early/write-late, ~64 outstanding VMEM/wave), pack+LDS
//      write as they drain, ONE barrier, then MFMA with wf read from L2.

typedef _Float16 half8 __attribute__((ext_vector_type(8)));
typedef float    floatx4 __attribute__((ext_vector_type(4)));

#define DHW  409600   // 16*160*160, per-channel stride in x/out
#define HW   25600    // 160*160

// ---- kernel 1: effective-weight fragments -> ws ---------------------------
// frag layout: ws[((t*2+p)*64 + l)*8 + j] = we[o=p*16+(l&15)][i=(l>>4)*8+j][t]
__global__ void bnn_wprep_kernel(const float* __restrict__ w,
                                 _Float16* __restrict__ ws) {
    const int tid = threadIdx.x;
    #pragma unroll
    for (int p4 = 0; p4 < 4; ++p4) {
        const int oi = tid * 4 + p4;       // oi = o*32 + i, 0..1023
        const int o  = oi >> 5;
        const int i  = oi & 31;
        const float* wp = w + oi * 9;
        float s = 0.f;
        #pragma unroll
        for (int t = 0; t < 9; ++t) s += fabsf(wp[t]);
        s *= (1.f / 9.f);
        const int l = ((i >> 3) << 4) | (o & 15);
        const int p = o >> 4;
        const int j = i & 7;
        #pragma unroll
        for (int t = 0; t < 9; ++t) {
            const float v  = wp[t];
            const float sg = (v > 0.f) ? 1.f : ((v < 0.f) ? -1.f : 0.f);
            ws[((t * 2 + p) * 64 + l) * 8 + j] = (_Float16)(s * sg);
        }
    }
}

// ---- kernel 2: the conv ---------------------------------------------------
__global__ __launch_bounds__(512, 4) void bnn_conv3d_kernel(
        const float* __restrict__ x, const _Float16* __restrict__ ws,
        float* __restrict__ out) {
    // x tile: [r:6][w1:162][ch:32] f16 = 62208 B, XOR-swizzled ch-groups.
    __shared__ __align__(16) _Float16 ldsh[31104];

    const int tid  = threadIdx.x;
    const int lane = tid & 63;
    const int wid  = tid >> 6;

    const int bid = blockIdx.x;
    const int ht  = bid % 40;          // h-tile
    const int nd  = bid / 40;
    const int d   = nd & 15;
    const int n   = nd >> 4;
    const int h0  = ht * 4;

    // ---------- phase 1: issue ALL staging loads (T14 issue-early) ---------
    // item idx = (r*4 + kg)*160 + wpos, 3840 items over 512 threads.
    float xv[8][8];
    #pragma unroll
    for (int it = 0; it < 8; ++it) {
        const bool active = (it < 7) || (tid < 256);
        const int idx  = it * 512 + tid;
        const int wpos = idx % 160;
        const int rest = idx / 160;
        const int kg   = rest & 3;
        const int r    = rest >> 2;
        const int h_in = h0 - 1 + r;
        if (active && (unsigned)h_in < 160u) {
            const float* src = x + ((n * 32 + kg * 8) * 16 + d) * HW
                                 + h_in * 160 + wpos;
            #pragma unroll
            for (int c = 0; c < 8; ++c) xv[it][c] = src[c * DHW];
        } else {
            #pragma unroll
            for (int c = 0; c < 8; ++c) xv[it][c] = 0.f;
        }
    }

    // zero halo columns w1 in {0,161}: 12 cells x 64 B (no vmcnt interaction)
    if (tid < 192) {
        const int pos = tid >> 4, word = tid & 15;
        const int r   = pos >> 1;
        const int w1  = (pos & 1) ? 161 : 0;
        reinterpret_cast<unsigned int*>(ldsh)[(r * 162 + w1) * 16 + word] = 0u;
    }

    // ---------- phase 2: pack + ds_write as loads drain (write-late) -------
    // logical (r,w1,ch): byte = (r*162+w1)*64 + ((ch>>3)^((w1>>1)&3))*16 + (ch&7)*2
    #pragma unroll
    for (int it = 0; it < 8; ++it) {
        const bool active = (it < 7) || (tid < 256);
        if (active) {
            const int idx  = it * 512 + tid;
            const int wpos = idx % 160;
            const int rest = idx / 160;
            const int kg   = rest & 3;
            const int r    = rest >> 2;
            half8 pk;
            #pragma unroll
            for (int c = 0; c < 8; ++c) pk[c] = (_Float16)xv[it][c];
            const int w1  = wpos + 1;
            const int skg = kg ^ ((w1 >> 1) & 3);
            *reinterpret_cast<half8*>(&ldsh[(r * 162 + w1) * 32 + skg * 8]) = pk;
        }
    }
    __syncthreads();   // the ONLY barrier

    // ---------- phase 3: wf from L2 + MFMA ---------------------------------
    half8 wf[2][9];
    {
        const half8* fb = reinterpret_cast<const half8*>(ws);
        #pragma unroll
        for (int t = 0; t < 9; ++t) {
            wf[0][t] = fb[(t * 2 + 0) * 64 + lane];
            wf[1][t] = fb[(t * 2 + 1) * 64 + lane];
        }
    }

    // wave wid: row = wid&3, w-half = wid>>2 (5 MFMA tiles each).
    // A-frag: lane l elem j = x_lds(r=row+kh, w1=wbase+(l&15)+kw, ch=(l>>4)*8+j)
    // D: row s=(l>>4)*4+reg (w offset), col o=l&15 (+16*p)
    const int s16   = lane & 15;
    const int kg    = lane >> 4;
    const int row   = wid & 3;
    const int whalf = wid >> 2;
    const int h     = h0 + row;
    const int obase = (n * 32 + s16) * DHW + d * HW + h * 160 + kg * 4;

    #pragma unroll
    for (int wtl = 0; wtl < 5; ++wtl) {
        const int wbase = (whalf * 5 + wtl) * 16;
        floatx4 acc0 = {0.f, 0.f, 0.f, 0.f};
        floatx4 acc1 = {0.f, 0.f, 0.f, 0.f};
        #pragma unroll
        for (int kh = 0; kh < 3; ++kh) {
            const int rrow = (row + kh) * 162;
            #pragma unroll
            for (int kw = 0; kw < 3; ++kw) {
                const int w1   = wbase + s16 + kw;
                const int aidx = (rrow + w1) * 32 + ((kg ^ ((w1 >> 1) & 3)) * 8);
                const half8 a  = *reinterpret_cast<const half8*>(&ldsh[aidx]);
                const int t = kh * 3 + kw;
                acc0 = __builtin_amdgcn_mfma_f32_16x16x32_f16(a, wf[0][t], acc0, 0, 0, 0);
                acc1 = __builtin_amdgcn_mfma_f32_16x16x32_f16(a, wf[1][t], acc1, 0, 0, 0);
            }
        }
        float* op = out + obase + wbase;
        *reinterpret_cast<floatx4*>(op)            = acc0;  // o = 0..15
        *reinterpret_cast<floatx4*>(op + 16 * DHW) = acc1;  // o = 16..31
    }
}

extern "C" void kernel_launch(void* const* d_in, const int* in_sizes, int n_in,
                              void* d_out, int out_size, void* d_ws, size_t ws_size,
                              hipStream_t stream) {
    const float* x = (const float*)d_in[0];
    const float* w = (const float*)d_in[1];
    float* out = (float*)d_out;
    _Float16* ws = (_Float16*)d_ws;     // 9216 halfs = 18 KB of scratch
    bnn_wprep_kernel<<<dim3(1), dim3(256), 0, stream>>>(w, ws);
    // grid: 8 n * 16 d * 40 h-tiles (full 160-w rows per block)
    bnn_conv3d_kernel<<<dim3(5120), dim3(512), 0, stream>>>(x, ws, out);
}

// Round 5
// 205.965 us; speedup vs baseline: 1.1117x; 1.1117x over previous
//
#include <hip/hip_runtime.h>

// BNN conv3d forward: x (8,32,16,160,160) f32, w (32,32,1,3,3) f32
// out[n,o,d,h,w] = sum_i sum_{kh,kw} x[n,i,d,h+kh-1,w+kw-1] * we[o,i,kh,kw]
// we[o,i,kh,kw] = (mean_t |w[o,i]|) * sign(w[o,i,kh,kw])
//
// Implicit GEMM on mfma_f32_16x16x32_f16. Two kernels:
//  (1) prep: weight fragments (18 KB) -> d_ws
//  (2) conv: block = 4 rows x 160 w, 512 thr. Staging via float4 loads
//      (8ch x 4w per item), ALL loads issued then sched_barrier(0) pins
//      them in flight; pack+ds_write after; one barrier; MFMA.
// LDS swizzle (derived for stride-4-lane b128 writes AND stride-1-lane reads):
//   cell:     w1x = w1 ^ ((w1>>2)&1)              (swaps 64B cells)
//   subblock: skg = kg ^ (((w1>>1)^(w1>>3))&3)    (16B sub-block in cell)
// -> writes hit 8 distinct bank-starts (conflict-free), reads ~2-way (free).

typedef _Float16 half8 __attribute__((ext_vector_type(8)));
typedef float    floatx4 __attribute__((ext_vector_type(4)));

#define DHW  409600   // 16*160*160, per-channel stride in x/out
#define HW   25600    // 160*160

__device__ __forceinline__ int lds_half_idx(int r, int w1, int kg) {
    const int w1x = w1 ^ ((w1 >> 2) & 1);
    const int skg = kg ^ (((w1 >> 1) ^ (w1 >> 3)) & 3);
    return (r * 162 + w1x) * 32 + skg * 8;
}

// ---- kernel 1: effective-weight fragments -> ws ---------------------------
// frag layout: ws[((t*2+p)*64 + l)*8 + j] = we[o=p*16+(l&15)][i=(l>>4)*8+j][t]
__global__ void bnn_wprep_kernel(const float* __restrict__ w,
                                 _Float16* __restrict__ ws) {
    const int tid = threadIdx.x;
    #pragma unroll
    for (int p4 = 0; p4 < 4; ++p4) {
        const int oi = tid * 4 + p4;       // oi = o*32 + i, 0..1023
        const int o  = oi >> 5;
        const int i  = oi & 31;
        const float* wp = w + oi * 9;
        float s = 0.f;
        #pragma unroll
        for (int t = 0; t < 9; ++t) s += fabsf(wp[t]);
        s *= (1.f / 9.f);
        const int l = ((i >> 3) << 4) | (o & 15);
        const int p = o >> 4;
        const int j = i & 7;
        #pragma unroll
        for (int t = 0; t < 9; ++t) {
            const float v  = wp[t];
            const float sg = (v > 0.f) ? 1.f : ((v < 0.f) ? -1.f : 0.f);
            ws[((t * 2 + p) * 64 + l) * 8 + j] = (_Float16)(s * sg);
        }
    }
}

// ---- kernel 2: the conv ---------------------------------------------------
__global__ __launch_bounds__(512, 4) void bnn_conv3d_kernel(
        const float* __restrict__ x, const _Float16* __restrict__ ws,
        float* __restrict__ out) {
    // x tile: 6 rows x 162 w1 x 32 ch f16 = 62208 B (swizzled, see top).
    __shared__ __align__(16) _Float16 ldsh[31104];

    const int tid  = threadIdx.x;
    const int lane = tid & 63;
    const int wid  = tid >> 6;

    const int bid = blockIdx.x;
    const int ht  = bid % 40;          // h-tile
    const int nd  = bid / 40;
    const int d   = nd & 15;
    const int n   = nd >> 4;
    const int h0  = ht * 4;

    // ---------- phase 1: issue ALL staging loads (float4 over w) -----------
    // item = (r:6, kg:4, wq:40) -> 960 items; thread owns idx0=tid, idx1=tid+512.
    const int  wq0 = tid % 40;
    const int  rs0 = tid / 40;
    const int  kg0 = rs0 & 3;
    const int  r0  = rs0 >> 2;
    const int  hi0 = h0 - 1 + r0;
    const bool v0l = (unsigned)hi0 < 160u;

    const bool act1 = tid < 448;       // waves 0..6 (wave-uniform)
    const int  id1  = tid + 512;
    const int  wq1 = id1 % 40;
    const int  rs1 = id1 / 40;
    const int  kg1 = rs1 & 3;
    const int  r1  = rs1 >> 2;
    const int  hi1 = h0 - 1 + r1;
    const bool v1l = act1 && ((unsigned)hi1 < 160u);

    floatx4 fl0[8], fl1[8];
    {
        const floatx4 z = {0.f, 0.f, 0.f, 0.f};
        const float* s0 = x + ((n * 32 + kg0 * 8) * 16 + d) * HW + hi0 * 160 + wq0 * 4;
        const float* s1 = x + ((n * 32 + kg1 * 8) * 16 + d) * HW + hi1 * 160 + wq1 * 4;
        #pragma unroll
        for (int c = 0; c < 8; ++c)
            fl0[c] = v0l ? *reinterpret_cast<const floatx4*>(s0 + c * DHW) : z;
        #pragma unroll
        for (int c = 0; c < 8; ++c)
            fl1[c] = v1l ? *reinterpret_cast<const floatx4*>(s1 + c * DHW) : z;
    }

    // zero halo cells w1 in {0,161} (map to themselves under the swizzle)
    if (tid < 192) {
        const int pos = tid >> 4, word = tid & 15;
        const int r   = pos >> 1;
        const int w1  = (pos & 1) ? 161 : 0;
        reinterpret_cast<unsigned int*>(ldsh)[(r * 162 + w1) * 16 + word] = 0u;
    }

    // pin the loads: nothing may move across this point
    __builtin_amdgcn_sched_barrier(0);

    // ---------- phase 2: pack + ds_write as loads drain --------------------
    #pragma unroll
    for (int u = 0; u < 4; ++u) {
        half8 pk;
        #pragma unroll
        for (int c = 0; c < 8; ++c) pk[c] = (_Float16)fl0[c][u];
        const int w1 = wq0 * 4 + 1 + u;
        *reinterpret_cast<half8*>(&ldsh[lds_half_idx(r0, w1, kg0)]) = pk;
    }
    if (act1) {
        #pragma unroll
        for (int u = 0; u < 4; ++u) {
            half8 pk;
            #pragma unroll
            for (int c = 0; c < 8; ++c) pk[c] = (_Float16)fl1[c][u];
            const int w1 = wq1 * 4 + 1 + u;
            *reinterpret_cast<half8*>(&ldsh[lds_half_idx(r1, w1, kg1)]) = pk;
        }
    }

    // ---------- issue wf loads (L2-resident), consumed after barrier -------
    half8 wf[2][9];
    {
        const half8* fb = reinterpret_cast<const half8*>(ws);
        #pragma unroll
        for (int t = 0; t < 9; ++t) {
            wf[0][t] = fb[(t * 2 + 0) * 64 + lane];
            wf[1][t] = fb[(t * 2 + 1) * 64 + lane];
        }
    }
    __syncthreads();   // the ONLY barrier

    // ---------- phase 3: MFMA ----------------------------------------------
    // wave wid: row = wid&3, w-half = wid>>2 (5 MFMA tiles each).
    // A-frag: lane l elem j = x_lds(r=row+kh, w1=wbase+(l&15)+kw, ch=(l>>4)*8+j)
    // D: row s=(l>>4)*4+reg (w offset), col o=l&15 (+16*p)
    const int s16   = lane & 15;
    const int kg    = lane >> 4;
    const int row   = wid & 3;
    const int whalf = wid >> 2;
    const int h     = h0 + row;
    const int obase = (n * 32 + s16) * DHW + d * HW + h * 160 + kg * 4;

    #pragma unroll
    for (int wtl = 0; wtl < 5; ++wtl) {
        const int wbase = (whalf * 5 + wtl) * 16;
        floatx4 acc0 = {0.f, 0.f, 0.f, 0.f};
        floatx4 acc1 = {0.f, 0.f, 0.f, 0.f};
        #pragma unroll
        for (int kw = 0; kw < 3; ++kw) {
            const int w1  = wbase + s16 + kw;
            const int w1x = w1 ^ ((w1 >> 2) & 1);
            const int sub = ((kg ^ (((w1 >> 1) ^ (w1 >> 3)) & 3)) * 8) + w1x * 32;
            #pragma unroll
            for (int kh = 0; kh < 3; ++kh) {
                const half8 a = *reinterpret_cast<const half8*>(
                        &ldsh[(row + kh) * (162 * 32) + sub]);
                const int t = kh * 3 + kw;
                acc0 = __builtin_amdgcn_mfma_f32_16x16x32_f16(a, wf[0][t], acc0, 0, 0, 0);
                acc1 = __builtin_amdgcn_mfma_f32_16x16x32_f16(a, wf[1][t], acc1, 0, 0, 0);
            }
        }
        float* op = out + obase + wbase;
        *reinterpret_cast<floatx4*>(op)            = acc0;  // o = 0..15
        *reinterpret_cast<floatx4*>(op + 16 * DHW) = acc1;  // o = 16..31
    }
}

extern "C" void kernel_launch(void* const* d_in, const int* in_sizes, int n_in,
                              void* d_out, int out_size, void* d_ws, size_t ws_size,
                              hipStream_t stream) {
    const float* x = (const float*)d_in[0];
    const float* w = (const float*)d_in[1];
    float* out = (float*)d_out;
    _Float16* ws = (_Float16*)d_ws;     // 9216 halfs = 18 KB of scratch
    bnn_wprep_kernel<<<dim3(1), dim3(256), 0, stream>>>(w, ws);
    // grid: 8 n * 16 d * 40 h-tiles (full 160-w rows per block)
    bnn_conv3d_kernel<<<dim3(5120), dim3(512), 0, stream>>>(x, ws, out);
}

// Round 6
// 204.114 us; speedup vs baseline: 1.1217x; 1.0091x over previous
//
#include <hip/hip_runtime.h>

// BNN conv3d forward: x (8,32,16,160,160) f32, w (32,32,1,3,3) f32
// out[n,o,d,h,w] = sum_i sum_{kh,kw} x[n,i,d,h+kh-1,w+kw-1] * we[o,i,kh,kw]
// we = (mean|w| over taps) * sign(w).  Implicit GEMM, mfma_f32_16x16x32_f16.
//
// Round-6 structure: rolling-ring pipeline (T3/T4). Block = 320 thr (5 waves)
// owns 20 output rows of one (n,d) slab. LDS ring = 6 row-slots (62 KB).
// Stage-unit S_k = input rows {2k-1, 2k}; tile C_t = output rows {2t, 2t+1}.
// Per tile: [BARRIER_A; pack S_{t+1}; BARRIER_B; issue S_{t+3} loads;
// compute C_t]. Loads live in named regsets A/B (static parity), stay in
// flight across RAW s_barriers (no __syncthreads -> no vmcnt(0) drain).
// Ring slot for local input row lh: (lh+1) % 6. Slot overwritten by pack(t)
// was last read by compute(t-2), two barriers earlier -> race-free.

typedef _Float16 half8 __attribute__((ext_vector_type(8)));
typedef float    floatx4 __attribute__((ext_vector_type(4)));

#define DHW  409600   // 16*160*160
#define HW   25600    // 160*160
#define ROWB (162*32) // halfs per ring row-slot

__device__ __forceinline__ int lds_half_idx(int slot, int w1, int kg) {
    // verified swizzle (round 5, bank-conflict-free): cell swap + sub-block XOR
    const int w1x = w1 ^ ((w1 >> 2) & 1);
    const int skg = kg ^ (((w1 >> 1) ^ (w1 >> 3)) & 3);
    return slot * ROWB + w1x * 32 + skg * 8;
}

__device__ __forceinline__ void barrier_raw() {
    // LDS-visibility barrier that does NOT drain vmcnt (loads stay in flight)
    __builtin_amdgcn_sched_barrier(0);
    asm volatile("s_waitcnt lgkmcnt(0)" ::: "memory");
    __builtin_amdgcn_s_barrier();
    __builtin_amdgcn_sched_barrier(0);
}

// ---- kernel 1: effective-weight fragments -> ws (18 KB) -------------------
// ws[((t*2+p)*64 + l)*8 + j] = we[o=p*16+(l&15)][i=(l>>4)*8+j][t]
__global__ void bnn_wprep_kernel(const float* __restrict__ w,
                                 _Float16* __restrict__ ws) {
    const int tid = threadIdx.x;
    #pragma unroll
    for (int p4 = 0; p4 < 4; ++p4) {
        const int oi = tid * 4 + p4;
        const int o  = oi >> 5;
        const int i  = oi & 31;
        const float* wp = w + oi * 9;
        float s = 0.f;
        #pragma unroll
        for (int t = 0; t < 9; ++t) s += fabsf(wp[t]);
        s *= (1.f / 9.f);
        const int l = ((i >> 3) << 4) | (o & 15);
        const int p = o >> 4;
        const int j = i & 7;
        #pragma unroll
        for (int t = 0; t < 9; ++t) {
            const float v  = wp[t];
            const float sg = (v > 0.f) ? 1.f : ((v < 0.f) ? -1.f : 0.f);
            ws[((t * 2 + p) * 64 + l) * 8 + j] = (_Float16)(s * sg);
        }
    }
}

struct SR { floatx4 v[8]; };   // one stage-unit's per-thread data (32 VGPR)

// ---- kernel 2: the conv ---------------------------------------------------
__global__ __launch_bounds__(320) void bnn_conv3d_ring(
        const float* __restrict__ x, const _Float16* __restrict__ ws,
        float* __restrict__ out) {
    __shared__ __align__(16) _Float16 ldsh[6 * ROWB];   // 62208 B ring

    const int tid  = threadIdx.x;
    const int lane = tid & 63;

    const int bid = blockIdx.x;        // 1024 = 8n * 16d * 8 h-chunks
    const int chk = bid & 7;
    const int nd  = bid >> 3;
    const int d   = nd & 15;
    const int n   = nd >> 4;
    const int h0  = chk * 20;          // block owns output rows h0..h0+19

    // staging coords: item = (rr:2, kg:4, wq:40) = 320 = blockDim
    const int wq   = tid % 40;
    const int kg_s = (tid / 40) & 3;
    const int rr   = tid / 160;        // 0/1: which row of the stage-unit
    const float* xcol = x + ((n * 32 + kg_s * 8) * 16 + d) * HW + wq * 4;

    // compute coords: wave f = w-fifth (32 w); per wave 2 rows x 2 wtiles
    const int s16  = lane & 15;
    const int kg_r = lane >> 4;
    const int f    = tid >> 6;
    int rdoff[2][3];
    #pragma unroll
    for (int wt = 0; wt < 2; ++wt)
        #pragma unroll
        for (int kw = 0; kw < 3; ++kw)
            rdoff[wt][kw] = lds_half_idx(0, f * 32 + wt * 16 + s16 + kw, kg_r);
    float* obase = out + (n * 32 + s16) * DHW + d * HW + kg_r * 4 + f * 32;

    // weight fragments (L2-resident table from prep kernel)
    half8 wf0[9], wf1[9];
    {
        const half8* fb = reinterpret_cast<const half8*>(ws);
        #pragma unroll
        for (int t = 0; t < 9; ++t) {
            wf0[t] = fb[(t * 2 + 0) * 64 + lane];
            wf1[t] = fb[(t * 2 + 1) * 64 + lane];
        }
    }

    auto ISSUE = [&](int k, SR& R) {   // issue loads for S_k (rows h0+2k-1+rr)
        const int h_in = h0 + 2 * k - 1 + rr;
        const floatx4 z = {0.f, 0.f, 0.f, 0.f};
        const float* p = xcol + h_in * 160;
        const bool ok = (unsigned)h_in < 160u;
        #pragma unroll
        for (int c = 0; c < 8; ++c)
            R.v[c] = ok ? *reinterpret_cast<const floatx4*>(p + c * DHW) : z;
    };
    auto PACK = [&](int k, SR& R) {    // cvt + ds_write S_k into ring
        const int slot = (2 * k + rr) % 6;
        #pragma unroll
        for (int u = 0; u < 4; ++u) {
            half8 pk;
            #pragma unroll
            for (int c = 0; c < 8; ++c) pk[c] = (_Float16)R.v[c][u];
            *reinterpret_cast<half8*>(
                &ldsh[lds_half_idx(slot, wq * 4 + 1 + u, kg_s)]) = pk;
        }
        if (wq == 0) {
            half8 zz = {};
            *reinterpret_cast<half8*>(&ldsh[lds_half_idx(slot, 0, kg_s)]) = zz;
        }
        if (wq == 39) {
            half8 zz = {};
            *reinterpret_cast<half8*>(&ldsh[lds_half_idx(slot, 161, kg_s)]) = zz;
        }
    };
    auto COMPUTE = [&](int t) {        // output rows h0+2t, h0+2t+1
        #pragma unroll
        for (int row_l = 0; row_l < 2; ++row_l) {
            #pragma unroll
            for (int wt = 0; wt < 2; ++wt) {
                floatx4 a0 = {0.f, 0.f, 0.f, 0.f};
                floatx4 a1 = {0.f, 0.f, 0.f, 0.f};
                #pragma unroll
                for (int kh = 0; kh < 3; ++kh) {
                    const int slot = (2 * t + row_l + kh) % 6;
                    const int so   = slot * ROWB;
                    #pragma unroll
                    for (int kw = 0; kw < 3; ++kw) {
                        const half8 a = *reinterpret_cast<const half8*>(
                                &ldsh[so + rdoff[wt][kw]]);
                        const int tap = kh * 3 + kw;
                        a0 = __builtin_amdgcn_mfma_f32_16x16x32_f16(a, wf0[tap], a0, 0, 0, 0);
                        a1 = __builtin_amdgcn_mfma_f32_16x16x32_f16(a, wf1[tap], a1, 0, 0, 0);
                    }
                }
                float* op = obase + (h0 + 2 * t + row_l) * 160 + wt * 16;
                *reinterpret_cast<floatx4*>(op)            = a0;  // o 0..15
                *reinterpret_cast<floatx4*>(op + 16 * DHW) = a1;  // o 16..31
            }
        }
    };

    // ---------------- pipeline ----------------
    SR A, B;
    ISSUE(0, A);
    ISSUE(1, B);
    PACK(0, A);        // slots fresh; no barrier needed yet
    ISSUE(2, A);
    // 10 tiles, unrolled by 2 for static A/B parity
    for (int tt = 0; tt < 5; ++tt) {
        const int t0 = 2 * tt;
        // even tile t0: pack S_{t0+1} (B), refill B with S_{t0+3}
        barrier_raw();                     // A: all done reading slots we rewrite
        PACK(t0 + 1, B);
        barrier_raw();                     // B: ring rows t0's tile needs visible
        if (t0 + 3 <= 10) ISSUE(t0 + 3, B);
        COMPUTE(t0);
        // odd tile t0+1: pack S_{t0+2} (A), refill A with S_{t0+4}
        barrier_raw();
        PACK(t0 + 2, A);
        barrier_raw();
        if (t0 + 4 <= 10) ISSUE(t0 + 4, A);
        COMPUTE(t0 + 1);
    }
}

extern "C" void kernel_launch(void* const* d_in, const int* in_sizes, int n_in,
                              void* d_out, int out_size, void* d_ws, size_t ws_size,
                              hipStream_t stream) {
    const float* x = (const float*)d_in[0];
    const float* w = (const float*)d_in[1];
    float* out = (float*)d_out;
    _Float16* ws = (_Float16*)d_ws;     // 9216 halfs = 18 KB scratch
    bnn_wprep_kernel<<<dim3(1), dim3(256), 0, stream>>>(w, ws);
    // grid: 8 n * 16 d * 8 h-chunks of 20 rows
    bnn_conv3d_ring<<<dim3(1024), dim3(320), 0, stream>>>(x, ws, out);
}